// Round 1
// baseline (4945.451 us; speedup 1.0000x reference)
//
#include <hip/hip_runtime.h>
#include <hip/hip_bf16.h>

// BiLSTM-CRF forward decode, f32 exact-path implementation.
// Phases:
//   A: embedding gather + input projection GEMM -> xp[dir][s][g][b]
//   B: persistent grid-synced LSTM scan (both directions in parallel)
//   C: feats = concat(hf,hb) @ Wout^T + bout
//   D: Viterbi scan + backtrace -> int32 tags

#define S_LEN 256
#define BATCH 32
#define NTAG  24
#define NBLK_LSTM 128   // 2 dirs * 64 chunks (4 hidden units each)

__device__ __forceinline__ int colperm(int k) {
  // bijective column permutation on [0,256): bit-swap of 4-float chunk index
  // so that a thread's k-slice (stride-32 chunks) lands on distinct LDS bank
  // granules. chunk c = k>>2 in [0,64): p = ((c&7)<<3)|(c>>3).
  int c = k >> 2;
  int p = ((c & 7) << 3) | (c >> 3);
  return p * 4 + (k & 3);
}

// ---------------------------------------------------------------- Phase A
__global__ __launch_bounds__(256) void k_inproj(
    const int* __restrict__ sent, const float* __restrict__ embed,
    const float* __restrict__ WihF, const float* __restrict__ bihF, const float* __restrict__ bhhF,
    const float* __restrict__ WihB, const float* __restrict__ bihB, const float* __restrict__ bhhB,
    float* __restrict__ xp) {
  int tm = blockIdx.x;   // 0..127 : 64 (s,b)-rows each
  int tn = blockIdx.y;   // 0..15  : 64 g-cols each
  int dir = blockIdx.z;
  const float* Wih = dir ? WihB : WihF;
  const float* bih = dir ? bihB : bihF;
  const float* bhh = dir ? bhhB : bhhF;
  __shared__ float As[64 * 36];
  __shared__ float Bs[64 * 36];
  __shared__ int toks[64];
  int tid = threadIdx.x;
  if (tid < 64) {
    int r = tm * 64 + tid;
    int s = r >> 5, b = r & 31;
    toks[tid] = sent[b * S_LEN + s];
  }
  __syncthreads();
  int mt = tid & 15, nt = tid >> 4;
  float acc[4][4] = {};
  for (int k0 = 0; k0 < 256; k0 += 32) {
    for (int it = 0; it < 2; ++it) {
      int u = it * 256 + tid;
      int row = u >> 3, lf = u & 7;
      float4 av = *(const float4*)&embed[(size_t)toks[row] * 256 + k0 + lf * 4];
      *(float4*)&As[row * 36 + lf * 4] = av;
      int grow = tn * 64 + row;
      float4 wv = *(const float4*)&Wih[(size_t)grow * 256 + k0 + lf * 4];
      *(float4*)&Bs[row * 36 + lf * 4] = wv;
    }
    __syncthreads();
#pragma unroll
    for (int kc = 0; kc < 8; ++kc) {
      float4 a[4], w[4];
#pragma unroll
      for (int i = 0; i < 4; ++i) a[i] = *(const float4*)&As[(mt + 16 * i) * 36 + kc * 4];
#pragma unroll
      for (int j = 0; j < 4; ++j) w[j] = *(const float4*)&Bs[(nt + 16 * j) * 36 + kc * 4];
#pragma unroll
      for (int i = 0; i < 4; ++i)
#pragma unroll
        for (int j = 0; j < 4; ++j)
          acc[i][j] += a[i].x * w[j].x + a[i].y * w[j].y + a[i].z * w[j].z + a[i].w * w[j].w;
    }
    __syncthreads();
  }
#pragma unroll
  for (int i = 0; i < 4; ++i) {
    int r = tm * 64 + mt + 16 * i;
    int s = r >> 5, b = r & 31;
#pragma unroll
    for (int j = 0; j < 4; ++j) {
      int g = tn * 64 + nt + 16 * j;
      float v = acc[i][j] + bih[g] + bhh[g];
      xp[(((size_t)dir * 256 + s) * 1024 + g) * 32 + b] = v;
    }
  }
}

// ---------------------------------------------------------------- Phase B
// Persistent kernel. block = (dir, chunk of 4 hidden units -> 16 Whh rows).
// Weights LDS-resident for the whole scan; h exchanged through global memory
// with device-scope relaxed atomics; per-step counter barrier.
__global__ __launch_bounds__(256) void k_lstm(
    const float* __restrict__ WhhF, const float* __restrict__ WhhB,
    const float* __restrict__ xp,
    float* __restrict__ hG,    // [2 parity][2 dir][32 b][256 col(permuted)]
    float* __restrict__ hsH,   // [2 dir][256 s][256 j][32 b]
    unsigned int* __restrict__ bar) {  // [256], zeroed per launch
  int bx = blockIdx.x;
  int dir = bx & 1;
  int chunk = bx >> 1;   // 0..63
  int j0 = chunk * 4;
  const float* Whh = dir ? WhhB : WhhF;
  int tid = threadIdx.x;
  int ks = tid & 7, rt = (tid >> 3) & 3, bt = tid >> 5;
  int r0 = rt * 4, b0 = bt * 4;

  __shared__ float Ws[16 * 260];   // 16 gate-rows x 256 (permuted cols), padded
  __shared__ float Hs[32 * 260];   // h staged per step, permuted cols
  __shared__ float Gt[16 * 32];    // gates
  __shared__ float Cp[4 * 32];     // cell state (block-owned units)

  for (int u = tid; u < 16 * 256; u += 256) {
    int r = u >> 8, k = u & 255;
    int gate = r >> 2, jj = r & 3;
    int grow = gate * 256 + j0 + jj;
    Ws[r * 260 + colperm(k)] = Whh[(size_t)grow * 256 + k];
  }
  if (tid < 128) Cp[tid] = 0.f;
  __syncthreads();

#pragma unroll 1
  for (int step = 0; step < 256; ++step) {
    int s = dir ? (255 - step) : step;
    int par = step & 1;
    // stage h(par,dir) -> LDS (device-scope loads: fresh across XCDs)
    {
      float* hp = hG + ((size_t)par * 2 + dir) * 32 * 256;
      for (int u = tid; u < 32 * 256; u += 256) {
        int b = u >> 8, c = u & 255;
        float v = __hip_atomic_load(&hp[b * 256 + c], __ATOMIC_RELAXED, __HIP_MEMORY_SCOPE_AGENT);
        Hs[b * 260 + c] = v;
      }
    }
    // prefetch this thread's xp contributions
    float xv[2];
    {
      const float* xps = xp + (((size_t)dir * 256 + s) * 1024) * 32;
#pragma unroll
      for (int e = 0; e < 2; ++e) {
        int idx = ks * 2 + e;
        int i = idx >> 2, j = idx & 3;
        int row = r0 + i;
        int gate = row >> 2, jj = row & 3;
        int g = gate * 256 + j0 + jj;
        xv[e] = xps[g * 32 + b0 + (idx & 3)];
      }
    }
    __syncthreads();
    // dot products: 4 rows x 4 b per thread over 32-k slice
    float acc[4][4] = {};
#pragma unroll
    for (int t = 0; t < 8; ++t) {
      int c = ks * 8 + t;
      int p = ((c & 7) << 3) | (c >> 3);
      int off = p * 4;
      float4 hv[4], wv[4];
#pragma unroll
      for (int j = 0; j < 4; ++j) hv[j] = *(const float4*)&Hs[(b0 + j) * 260 + off];
#pragma unroll
      for (int i = 0; i < 4; ++i) wv[i] = *(const float4*)&Ws[(r0 + i) * 260 + off];
#pragma unroll
      for (int i = 0; i < 4; ++i)
#pragma unroll
        for (int j = 0; j < 4; ++j)
          acc[i][j] += wv[i].x * hv[j].x + wv[i].y * hv[j].y + wv[i].z * hv[j].z + wv[i].w * hv[j].w;
    }
    // reduce the 8-way k-split across lanes (ks = lane bits 0..2)
#pragma unroll
    for (int i = 0; i < 4; ++i)
#pragma unroll
      for (int j = 0; j < 4; ++j) {
        float v = acc[i][j];
        v += __shfl_xor(v, 1);
        v += __shfl_xor(v, 2);
        v += __shfl_xor(v, 4);
        acc[i][j] = v;
      }
    // lane ks writes gate entries 2ks, 2ks+1 (+xp)
#pragma unroll
    for (int e = 0; e < 2; ++e) {
      int idx = ks * 2 + e;
      int i = idx >> 2, j = idx & 3;
      int row = r0 + i;
      Gt[row * 32 + b0 + j] = acc[i][j] + xv[e];
    }
    __syncthreads();
    // gate nonlinearities + state update for 4 units x 32 b
    if (tid < 128) {
      int jj = tid >> 5, b = tid & 31;
      float xi = Gt[(0 + jj) * 32 + b];
      float xf = Gt[(4 + jj) * 32 + b];
      float xg = Gt[(8 + jj) * 32 + b];
      float xo = Gt[(12 + jj) * 32 + b];
      float si = 1.f / (1.f + expf(-xi));
      float sf = 1.f / (1.f + expf(-xf));
      float so = 1.f / (1.f + expf(-xo));
      float tg = tanhf(xg);
      float c = sf * Cp[jj * 32 + b] + si * tg;
      Cp[jj * 32 + b] = c;
      float h = so * tanhf(c);
      int jg = j0 + jj;
      float* hn = hG + ((size_t)(par ^ 1) * 2 + dir) * 32 * 256;
      __hip_atomic_store(&hn[b * 256 + colperm(jg)], h, __ATOMIC_RELAXED, __HIP_MEMORY_SCOPE_AGENT);
      hsH[(((size_t)dir * 256 + s) * 256 + jg) * 32 + b] = h;
    }
    __syncthreads();   // drains vmcnt: all h stores complete before arrive
    if (tid == 0) {
      __hip_atomic_fetch_add(&bar[step], 1u, __ATOMIC_RELEASE, __HIP_MEMORY_SCOPE_AGENT);
      unsigned spins = 0;
      while (__hip_atomic_load(&bar[step], __ATOMIC_ACQUIRE, __HIP_MEMORY_SCOPE_AGENT) < NBLK_LSTM) {
        __builtin_amdgcn_s_sleep(1);
        if (++spins > (1u << 22)) break;   // safety: never hang the harness
      }
    }
    __syncthreads();
  }
}

// ---------------------------------------------------------------- Phase C
__global__ __launch_bounds__(256) void k_feats(
    const float* __restrict__ hsH, const float* __restrict__ Wout,
    const float* __restrict__ bout, float* __restrict__ feats) {
  int s = blockIdx.x;
  int tid = threadIdx.x;
  __shared__ float Hl[32 * 260];
  __shared__ float Wl[24 * 260];
  float acc[3] = {};
  for (int dir = 0; dir < 2; ++dir) {
    __syncthreads();
    for (int u = tid; u < 8192; u += 256) {
      int j = u >> 5, b = u & 31;
      Hl[b * 260 + j] = hsH[(((size_t)dir * 256 + s) * 256 + j) * 32 + b];
    }
    for (int u = tid; u < 24 * 256; u += 256) {
      int t = u >> 8, j = u & 255;
      Wl[t * 260 + j] = Wout[t * 512 + dir * 256 + j];
    }
    __syncthreads();
    int b = tid & 31, th = tid >> 5;
    for (int jc = 0; jc < 64; ++jc) {
      float4 hv = *(const float4*)&Hl[b * 260 + jc * 4];
#pragma unroll
      for (int rep = 0; rep < 3; ++rep) {
        int t = rep * 8 + th;
        float4 wv = *(const float4*)&Wl[t * 260 + jc * 4];
        acc[rep] += hv.x * wv.x + hv.y * wv.y + hv.z * wv.z + hv.w * wv.w;
      }
    }
  }
  int b = tid & 31, th = tid >> 5;
#pragma unroll
  for (int rep = 0; rep < 3; ++rep) {
    int t = rep * 8 + th;
    feats[((size_t)s * 32 + b) * 24 + t] = acc[rep] + bout[t];
  }
}

// ---------------------------------------------------------------- Phase D
__global__ __launch_bounds__(64) void k_viterbi(
    const float* __restrict__ feats, const float* __restrict__ trans,
    const float* __restrict__ start_t, const float* __restrict__ stop_t,
    int* __restrict__ out) {
  int b = blockIdx.x;
  int j = threadIdx.x;
  bool act = j < NTAG;
  int j2 = act ? j : 0;
  __shared__ unsigned char idxL[255 * 24];
  __shared__ float sv[32];
  float tr[24];
#pragma unroll
  for (int i = 0; i < 24; ++i) tr[i] = trans[i * 24 + j2];
  float vj = feats[(size_t)b * 24 + j2] + start_t[j2];   // s=0: (0*32+b)*24
  if (!act) vj = -1e30f;
#pragma unroll 1
  for (int s = 1; s < 256; ++s) {
    float m = -1e30f;
    int arg = 0;
#pragma unroll
    for (int i = 0; i < 24; ++i) {
      float vi = __shfl(vj, i);
      float sc = vi + tr[i];
      if (sc > m) { m = sc; arg = i; }   // strict > keeps FIRST max (argmax semantics)
    }
    float fj = feats[((size_t)s * 32 + b) * 24 + j2];
    if (act) {
      idxL[(s - 1) * 24 + j] = (unsigned char)arg;
      vj = m + fj;
    }
  }
  if (act) sv[j] = vj + stop_t[j];
  __syncthreads();
  if (j == 0) {
    float m = sv[0];
    int tag = 0;
    for (int i = 1; i < 24; ++i)
      if (sv[i] > m) { m = sv[i]; tag = i; }
    out[b * 256 + 255] = tag;
    for (int s = 254; s >= 0; --s) {
      tag = idxL[s * 24 + tag];
      out[b * 256 + s] = tag;
    }
  }
}

// ---------------------------------------------------------------- host
extern "C" void kernel_launch(void* const* d_in, const int* in_sizes, int n_in,
                              void* d_out, int out_size, void* d_ws, size_t ws_size,
                              hipStream_t stream) {
  const int*   sent   = (const int*)  d_in[0];
  const float* embed  = (const float*)d_in[1];
  const float* WihF   = (const float*)d_in[2];
  const float* WhhF   = (const float*)d_in[3];
  const float* bihF   = (const float*)d_in[4];
  const float* bhhF   = (const float*)d_in[5];
  const float* WihB   = (const float*)d_in[6];
  const float* WhhB   = (const float*)d_in[7];
  const float* bihB   = (const float*)d_in[8];
  const float* bhhB   = (const float*)d_in[9];
  const float* Wout   = (const float*)d_in[10];
  const float* bout   = (const float*)d_in[11];
  const float* trans  = (const float*)d_in[12];
  const float* startt = (const float*)d_in[13];
  const float* stopt  = (const float*)d_in[14];
  int* out = (int*)d_out;

  char* ws = (char*)d_ws;
  size_t off = 0;
  float* xp = (float*)(ws + off);           off += (size_t)2 * 256 * 1024 * 32 * 4;  // 64 MB
  size_t off_sync = off;
  float* hG = (float*)(ws + off);           off += (size_t)2 * 2 * 32 * 256 * 4;     // 256 KB
  unsigned int* bar = (unsigned int*)(ws + off); off += 256 * 4;                     // 1 KB
  size_t sync_len = off - off_sync;
  float* hsH = (float*)(ws + off);          off += (size_t)2 * 256 * 256 * 32 * 4;   // 16 MB
  float* feats = (float*)(ws + off);        off += (size_t)256 * 32 * 24 * 4;        // 768 KB

  // zero h ping-pong buffers + barrier counters (required every launch:
  // barrier counters are consumed monotonically within one kernel execution)
  hipMemsetAsync(ws + off_sync, 0, sync_len, stream);

  k_inproj<<<dim3(128, 16, 2), 256, 0, stream>>>(sent, embed, WihF, bihF, bhhF,
                                                 WihB, bihB, bhhB, xp);
  k_lstm<<<NBLK_LSTM, 256, 0, stream>>>(WhhF, WhhB, xp, hG, hsH, bar);
  k_feats<<<256, 256, 0, stream>>>(hsH, Wout, bout, feats);
  k_viterbi<<<32, 64, 0, stream>>>(feats, trans, startt, stopt, out);
}

// Round 2
// 4606.631 us; speedup vs baseline: 1.0736x; 1.0736x over previous
//
#include <hip/hip_runtime.h>
#include <hip/hip_bf16.h>

// BiLSTM-CRF forward decode, f32 exact-path implementation.
// Phases:
//   A: embedding gather + input projection GEMM -> xp[dir][s][g][b]
//   B: persistent LSTM scan, flag-based (no-RMW) inter-block sync
//   C: feats = concat(hf,hb) @ Wout^T + bout
//   D: Viterbi scan + backtrace -> int32 tags

#define S_LEN 256
#define BATCH 32
#define NTAG  24
#define NBLK_LSTM 128   // 2 dirs * 64 chunks (4 hidden units each)

__device__ __forceinline__ int colperm(int k) {
  // bijective column permutation on [0,256): bit-swap of 4-float chunk index
  // so that a thread's k-slice (stride-32 chunks) lands on distinct LDS bank
  // granules. chunk c = k>>2 in [0,64): p = ((c&7)<<3)|(c>>3).
  int c = k >> 2;
  int p = ((c & 7) << 3) | (c >> 3);
  return p * 4 + (k & 3);
}

// ---------------------------------------------------------------- Phase A
__global__ __launch_bounds__(256) void k_inproj(
    const int* __restrict__ sent, const float* __restrict__ embed,
    const float* __restrict__ WihF, const float* __restrict__ bihF, const float* __restrict__ bhhF,
    const float* __restrict__ WihB, const float* __restrict__ bihB, const float* __restrict__ bhhB,
    float* __restrict__ xp) {
  int tm = blockIdx.x;   // 0..127 : 64 (s,b)-rows each
  int tn = blockIdx.y;   // 0..15  : 64 g-cols each
  int dir = blockIdx.z;
  const float* Wih = dir ? WihB : WihF;
  const float* bih = dir ? bihB : bihF;
  const float* bhh = dir ? bhhB : bhhF;
  __shared__ float As[64 * 36];
  __shared__ float Bs[64 * 36];
  __shared__ int toks[64];
  int tid = threadIdx.x;
  if (tid < 64) {
    int r = tm * 64 + tid;
    int s = r >> 5, b = r & 31;
    toks[tid] = sent[b * S_LEN + s];
  }
  __syncthreads();
  int mt = tid & 15, nt = tid >> 4;
  float acc[4][4] = {};
  for (int k0 = 0; k0 < 256; k0 += 32) {
    for (int it = 0; it < 2; ++it) {
      int u = it * 256 + tid;
      int row = u >> 3, lf = u & 7;
      float4 av = *(const float4*)&embed[(size_t)toks[row] * 256 + k0 + lf * 4];
      *(float4*)&As[row * 36 + lf * 4] = av;
      int grow = tn * 64 + row;
      float4 wv = *(const float4*)&Wih[(size_t)grow * 256 + k0 + lf * 4];
      *(float4*)&Bs[row * 36 + lf * 4] = wv;
    }
    __syncthreads();
#pragma unroll
    for (int kc = 0; kc < 8; ++kc) {
      float4 a[4], w[4];
#pragma unroll
      for (int i = 0; i < 4; ++i) a[i] = *(const float4*)&As[(mt + 16 * i) * 36 + kc * 4];
#pragma unroll
      for (int j = 0; j < 4; ++j) w[j] = *(const float4*)&Bs[(nt + 16 * j) * 36 + kc * 4];
#pragma unroll
      for (int i = 0; i < 4; ++i)
#pragma unroll
        for (int j = 0; j < 4; ++j)
          acc[i][j] += a[i].x * w[j].x + a[i].y * w[j].y + a[i].z * w[j].z + a[i].w * w[j].w;
    }
    __syncthreads();
  }
#pragma unroll
  for (int i = 0; i < 4; ++i) {
    int r = tm * 64 + mt + 16 * i;
    int s = r >> 5, b = r & 31;
#pragma unroll
    for (int j = 0; j < 4; ++j) {
      int g = tn * 64 + nt + 16 * j;
      float v = acc[i][j] + bih[g] + bhh[g];
      xp[(((size_t)dir * 256 + s) * 1024 + g) * 32 + b] = v;
    }
  }
}

// ---------------------------------------------------------------- Phase B
// Persistent kernel. block = (dir, chunk of 4 hidden units -> 16 Whh rows).
// Weights LDS-resident for the whole scan; h exchanged through global memory
// (agent-scope coherent loads/stores). Per-step sync: each block publishes
// flag[blk]=step+1 with ONE release store (no RMW -> no LLC serialization);
// wave 0 polls the 64 flags of its direction with relaxed vector loads.
__global__ __launch_bounds__(256) void k_lstm(
    const float* __restrict__ WhhF, const float* __restrict__ WhhB,
    const float* __restrict__ xp,
    float* __restrict__ hG,    // [2 parity][2 dir][32 b][256 col(permuted)]
    float* __restrict__ hsH,   // [2 dir][256 s][256 j][32 b]
    unsigned int* __restrict__ flags) {  // [2 dir][64 chunk], zeroed per launch
  int bx = blockIdx.x;
  int dir = bx & 1;
  int chunk = bx >> 1;   // 0..63
  int j0 = chunk * 4;
  const float* Whh = dir ? WhhB : WhhF;
  int tid = threadIdx.x;
  int ks = tid & 7, rt = (tid >> 3) & 3, bt = tid >> 5;
  int r0 = rt * 4, b0 = bt * 4;

  __shared__ float Ws[16 * 260];   // 16 gate-rows x 256 (permuted cols), padded
  __shared__ float Hs[32 * 260];   // h staged per step, permuted cols
  __shared__ float Gt[16 * 32];    // gates
  __shared__ float Cp[4 * 32];     // cell state (block-owned units)

  for (int u = tid; u < 16 * 256; u += 256) {
    int r = u >> 8, k = u & 255;
    int gate = r >> 2, jj = r & 3;
    int grow = gate * 256 + j0 + jj;
    Ws[r * 260 + colperm(k)] = Whh[(size_t)grow * 256 + k];
  }
  if (tid < 128) Cp[tid] = 0.f;
  __syncthreads();

#pragma unroll 1
  for (int step = 0; step < 256; ++step) {
    int s = dir ? (255 - step) : step;
    int par = step & 1;
    // prefetch this thread's xp contributions (independent of sync - issue
    // first so HBM/L2 latency hides under the flag wait)
    float xv[2];
    {
      const float* xps = xp + (((size_t)dir * 256 + s) * 1024) * 32;
#pragma unroll
      for (int e = 0; e < 2; ++e) {
        int idx = ks * 2 + e;
        int i = idx >> 2;
        int row = r0 + i;
        int gate = row >> 2, jj = row & 3;
        int g = gate * 256 + j0 + jj;
        xv[e] = xps[g * 32 + b0 + (idx & 3)];
      }
    }
    // wait until every block of this direction has published step `step`
    // (step 0: flags are 0 >= 0, passes immediately)
    if (tid < 64) {
      unsigned tgt = (unsigned)step;
      unsigned spins = 0;
      while (true) {
        unsigned v = __hip_atomic_load(&flags[dir * 64 + tid], __ATOMIC_RELAXED,
                                       __HIP_MEMORY_SCOPE_AGENT);
        if (__all(v >= tgt)) break;
        __builtin_amdgcn_s_sleep(1);
        if (++spins > (1u << 22)) break;   // safety: never hang the harness
      }
    }
    __syncthreads();   // all waves held until flags are ready
    // stage h(par,dir) -> LDS (agent-scope loads: coherent across XCDs)
    {
      float* hp = hG + ((size_t)par * 2 + dir) * 32 * 256;
      for (int u = tid; u < 32 * 256; u += 256) {
        int b = u >> 8, c = u & 255;
        float v = __hip_atomic_load(&hp[b * 256 + c], __ATOMIC_RELAXED, __HIP_MEMORY_SCOPE_AGENT);
        Hs[b * 260 + c] = v;
      }
    }
    __syncthreads();
    // dot products: 4 rows x 4 b per thread over 32-k slice
    float acc[4][4] = {};
#pragma unroll
    for (int t = 0; t < 8; ++t) {
      int c = ks * 8 + t;
      int p = ((c & 7) << 3) | (c >> 3);
      int off = p * 4;
      float4 hv[4], wv[4];
#pragma unroll
      for (int j = 0; j < 4; ++j) hv[j] = *(const float4*)&Hs[(b0 + j) * 260 + off];
#pragma unroll
      for (int i = 0; i < 4; ++i) wv[i] = *(const float4*)&Ws[(r0 + i) * 260 + off];
#pragma unroll
      for (int i = 0; i < 4; ++i)
#pragma unroll
        for (int j = 0; j < 4; ++j)
          acc[i][j] += wv[i].x * hv[j].x + wv[i].y * hv[j].y + wv[i].z * hv[j].z + wv[i].w * hv[j].w;
    }
    // reduce the 8-way k-split across lanes (ks = lane bits 0..2)
#pragma unroll
    for (int i = 0; i < 4; ++i)
#pragma unroll
      for (int j = 0; j < 4; ++j) {
        float v = acc[i][j];
        v += __shfl_xor(v, 1);
        v += __shfl_xor(v, 2);
        v += __shfl_xor(v, 4);
        acc[i][j] = v;
      }
    // lane ks writes gate entries 2ks, 2ks+1 (+xp)
#pragma unroll
    for (int e = 0; e < 2; ++e) {
      int idx = ks * 2 + e;
      int i = idx >> 2, j = idx & 3;
      int row = r0 + i;
      Gt[row * 32 + b0 + j] = acc[i][j] + xv[e];
    }
    __syncthreads();
    // gate nonlinearities + state update for 4 units x 32 b
    if (tid < 128) {
      int jj = tid >> 5, b = tid & 31;
      float xi = Gt[(0 + jj) * 32 + b];
      float xf = Gt[(4 + jj) * 32 + b];
      float xg = Gt[(8 + jj) * 32 + b];
      float xo = Gt[(12 + jj) * 32 + b];
      float si = 1.f / (1.f + expf(-xi));
      float sf = 1.f / (1.f + expf(-xf));
      float so = 1.f / (1.f + expf(-xo));
      float tg = tanhf(xg);
      float c = sf * Cp[jj * 32 + b] + si * tg;
      Cp[jj * 32 + b] = c;
      float h = so * tanhf(c);
      int jg = j0 + jj;
      float* hn = hG + ((size_t)(par ^ 1) * 2 + dir) * 32 * 256;
      __hip_atomic_store(&hn[b * 256 + colperm(jg)], h, __ATOMIC_RELAXED, __HIP_MEMORY_SCOPE_AGENT);
      hsH[(((size_t)dir * 256 + s) * 256 + jg) * 32 + b] = h;
    }
    __syncthreads();   // compiler emits s_waitcnt vmcnt(0) per wave before
                       // s_barrier -> ALL h stores are at the coherence point
    if (tid == 0) {
      // publish: one release store, own cache-line slot, no RMW
      __hip_atomic_store(&flags[dir * 64 + chunk], (unsigned)(step + 1),
                         __ATOMIC_RELEASE, __HIP_MEMORY_SCOPE_AGENT);
    }
    // NOTE: no trailing barrier needed - next iteration's flag wait gates
    // every consumer, and hG buffers ping-pong by parity.
  }
}

// ---------------------------------------------------------------- Phase C
__global__ __launch_bounds__(256) void k_feats(
    const float* __restrict__ hsH, const float* __restrict__ Wout,
    const float* __restrict__ bout, float* __restrict__ feats) {
  int s = blockIdx.x;
  int tid = threadIdx.x;
  __shared__ float Hl[32 * 260];
  __shared__ float Wl[24 * 260];
  float acc[3] = {};
  for (int dir = 0; dir < 2; ++dir) {
    __syncthreads();
    for (int u = tid; u < 8192; u += 256) {
      int j = u >> 5, b = u & 31;
      Hl[b * 260 + j] = hsH[(((size_t)dir * 256 + s) * 256 + j) * 32 + b];
    }
    for (int u = tid; u < 24 * 256; u += 256) {
      int t = u >> 8, j = u & 255;
      Wl[t * 260 + j] = Wout[t * 512 + dir * 256 + j];
    }
    __syncthreads();
    int b = tid & 31, th = tid >> 5;
    for (int jc = 0; jc < 64; ++jc) {
      float4 hv = *(const float4*)&Hl[b * 260 + jc * 4];
#pragma unroll
      for (int rep = 0; rep < 3; ++rep) {
        int t = rep * 8 + th;
        float4 wv = *(const float4*)&Wl[t * 260 + jc * 4];
        acc[rep] += hv.x * wv.x + hv.y * wv.y + hv.z * wv.z + hv.w * wv.w;
      }
    }
  }
  int b = tid & 31, th = tid >> 5;
#pragma unroll
  for (int rep = 0; rep < 3; ++rep) {
    int t = rep * 8 + th;
    feats[((size_t)s * 32 + b) * 24 + t] = acc[rep] + bout[t];
  }
}

// ---------------------------------------------------------------- Phase D
__global__ __launch_bounds__(64) void k_viterbi(
    const float* __restrict__ feats, const float* __restrict__ trans,
    const float* __restrict__ start_t, const float* __restrict__ stop_t,
    int* __restrict__ out) {
  int b = blockIdx.x;
  int j = threadIdx.x;
  bool act = j < NTAG;
  int j2 = act ? j : 0;
  __shared__ unsigned char idxL[255 * 24];
  __shared__ float sv[32];
  float tr[24];
#pragma unroll
  for (int i = 0; i < 24; ++i) tr[i] = trans[i * 24 + j2];
  float vj = feats[(size_t)b * 24 + j2] + start_t[j2];   // s=0: (0*32+b)*24
  if (!act) vj = -1e30f;
#pragma unroll 1
  for (int s = 1; s < 256; ++s) {
    float m = -1e30f;
    int arg = 0;
#pragma unroll
    for (int i = 0; i < 24; ++i) {
      float vi = __shfl(vj, i);
      float sc = vi + tr[i];
      if (sc > m) { m = sc; arg = i; }   // strict > keeps FIRST max (argmax semantics)
    }
    float fj = feats[((size_t)s * 32 + b) * 24 + j2];
    if (act) {
      idxL[(s - 1) * 24 + j] = (unsigned char)arg;
      vj = m + fj;
    }
  }
  if (act) sv[j] = vj + stop_t[j];
  __syncthreads();
  if (j == 0) {
    float m = sv[0];
    int tag = 0;
    for (int i = 1; i < 24; ++i)
      if (sv[i] > m) { m = sv[i]; tag = i; }
    out[b * 256 + 255] = tag;
    for (int s = 254; s >= 0; --s) {
      tag = idxL[s * 24 + tag];
      out[b * 256 + s] = tag;
    }
  }
}

// ---------------------------------------------------------------- host
extern "C" void kernel_launch(void* const* d_in, const int* in_sizes, int n_in,
                              void* d_out, int out_size, void* d_ws, size_t ws_size,
                              hipStream_t stream) {
  const int*   sent   = (const int*)  d_in[0];
  const float* embed  = (const float*)d_in[1];
  const float* WihF   = (const float*)d_in[2];
  const float* WhhF   = (const float*)d_in[3];
  const float* bihF   = (const float*)d_in[4];
  const float* bhhF   = (const float*)d_in[5];
  const float* WihB   = (const float*)d_in[6];
  const float* WhhB   = (const float*)d_in[7];
  const float* bihB   = (const float*)d_in[8];
  const float* bhhB   = (const float*)d_in[9];
  const float* Wout   = (const float*)d_in[10];
  const float* bout   = (const float*)d_in[11];
  const float* trans  = (const float*)d_in[12];
  const float* startt = (const float*)d_in[13];
  const float* stopt  = (const float*)d_in[14];
  int* out = (int*)d_out;

  char* ws = (char*)d_ws;
  size_t off = 0;
  float* xp = (float*)(ws + off);           off += (size_t)2 * 256 * 1024 * 32 * 4;  // 64 MB
  size_t off_sync = off;
  float* hG = (float*)(ws + off);           off += (size_t)2 * 2 * 32 * 256 * 4;     // 256 KB
  unsigned int* flags = (unsigned int*)(ws + off); off += 128 * 4;
  size_t sync_len = off - off_sync;
  float* hsH = (float*)(ws + off);          off += (size_t)2 * 256 * 256 * 32 * 4;   // 16 MB
  float* feats = (float*)(ws + off);        off += (size_t)256 * 32 * 24 * 4;        // 768 KB

  // zero h ping-pong buffers + flags (flags are consumed monotonically within
  // one kernel execution -> must be re-zeroed every launch/replay)
  hipMemsetAsync(ws + off_sync, 0, sync_len, stream);

  k_inproj<<<dim3(128, 16, 2), 256, 0, stream>>>(sent, embed, WihF, bihF, bhhF,
                                                 WihB, bihB, bhhB, xp);
  k_lstm<<<NBLK_LSTM, 256, 0, stream>>>(WhhF, WhhB, xp, hG, hsH, flags);
  k_feats<<<256, 256, 0, stream>>>(hsH, Wout, bout, feats);
  k_viterbi<<<32, 64, 0, stream>>>(feats, trans, startt, stopt, out);
}